// Round 3
// baseline (72543.488 us; speedup 1.0000x reference)
//
#include <hip/hip_runtime.h>

// Dtype is detected at RUNTIME (R1/R2 both NaN'd identically with bf16-input
// assumption across two different ws layouts => systematic dtype mismatch).
// in_g is ones(H): fp32 word0 = 0x3F800000, bf16 word0 = 0x3F803F80.
// flag: 0 = fp32 tensors, 1 = bf16 tensors. Internal canonical: bf16 matrices,
// fp32 state/vectors.

typedef unsigned short bf16_t;

__device__ __forceinline__ float bf2f(bf16_t u) {
    return __uint_as_float(((unsigned)u) << 16);
}
__device__ __forceinline__ bf16_t f2bf(float f) {
    unsigned u = __float_as_uint(f);
    unsigned r = (u + 0x7FFFu + ((u >> 16) & 1u)) >> 16;  // RNE
    return (bf16_t)r;
}

#define B_  8
#define S_  2048
#define H_  1024
#define EPS 1e-5f

// ---------------------------------------------------------------------------
__global__ void detect_flag(const unsigned* __restrict__ in_g_bits, int* flag) {
    *flag = (in_g_bits[0] == 0x3F800000u) ? 0 : 1;
}

// ---------------------------------------------------------------------------
// Canonicalize 9 H-length vectors to fp32. grid = (H/256, 9).
__global__ __launch_bounds__(256) void canon_vec(
    const void* v0, const void* v1, const void* v2, const void* v3,
    const void* v4, const void* v5, const void* v6, const void* v7,
    const void* v8, float* __restrict__ dst, const int* __restrict__ flagp)
{
    int isbf = *flagp;
    const void* srcs[9] = {v0, v1, v2, v3, v4, v5, v6, v7, v8};
    const void* s = srcs[blockIdx.y];
    int k = blockIdx.x * 256 + threadIdx.x;
    float val = isbf ? bf2f(((const bf16_t*)s)[k]) : ((const float*)s)[k];
    dst[(long)blockIdx.y * H_ + k] = val;
}

// ---------------------------------------------------------------------------
// Canonicalize h-part weight slices W[:, H:2H] -> contiguous bf16 [H,H].
// grid = (H, 3), 256 threads.
__global__ __launch_bounds__(256) void canon_wh(
    const void* Wu, const void* Wr, const void* Wo,
    bf16_t* __restrict__ Whu, bf16_t* __restrict__ Whr, bf16_t* __restrict__ Who,
    const int* __restrict__ flagp)
{
    int isbf = *flagp;
    const void* srcs[3] = {Wu, Wr, Wo};
    bf16_t* dsts[3] = {Whu, Whr, Who};
    const void* s = srcs[blockIdx.y];
    bf16_t* d = dsts[blockIdx.y];
    long j = blockIdx.x;
#pragma unroll
    for (int i = 0; i < 4; i++) {
        int k = threadIdx.x + i * 256;
        long off = j * (2 * H_) + H_ + k;
        bf16_t v = isbf ? ((const bf16_t*)s)[off] : f2bf(((const float*)s)[off]);
        d[j * H_ + k] = v;
    }
}

// ---------------------------------------------------------------------------
// Input layernorm: flag-dtype src -> bf16 dst. One block per row, 256 threads.
__global__ __launch_bounds__(256) void ln_in(
    const void* __restrict__ src, const float* __restrict__ g,
    const float* __restrict__ bt, bf16_t* __restrict__ dst,
    const int* __restrict__ flagp)
{
    int isbf = *flagp;
    long row = blockIdx.x;
    float v[4];
    float s = 0.f, q = 0.f;
#pragma unroll
    for (int i = 0; i < 4; i++) {
        long idx = row * H_ + threadIdx.x + i * 256;
        v[i] = isbf ? bf2f(((const bf16_t*)src)[idx]) : ((const float*)src)[idx];
        s += v[i];
        q += v[i] * v[i];
    }
#pragma unroll
    for (int off = 32; off; off >>= 1) {
        s += __shfl_down(s, off);
        q += __shfl_down(q, off);
    }
    __shared__ float ls[4], lq[4];
    __shared__ float smu, sri;
    int wid = threadIdx.x >> 6, lane = threadIdx.x & 63;
    if (lane == 0) { ls[wid] = s; lq[wid] = q; }
    __syncthreads();
    if (threadIdx.x == 0) {
        float S = ls[0] + ls[1] + ls[2] + ls[3];
        float Q = lq[0] + lq[1] + lq[2] + lq[3];
        float mu = S * (1.f / H_);
        smu = mu;
        sri = rsqrtf(Q * (1.f / H_) - mu * mu + EPS);
    }
    __syncthreads();
    float mu = smu, ri = sri;
#pragma unroll
    for (int i = 0; i < 4; i++) {
        int k = threadIdx.x + i * 256;
        dst[row * H_ + k] = f2bf((v[i] - mu) * ri * g[k] + bt[k]);
    }
}

// ---------------------------------------------------------------------------
// Final layernorm, in place on out, dtype per flag. One block per row.
__global__ __launch_bounds__(256) void ln_out(
    void* __restrict__ buf, const float* __restrict__ g,
    const float* __restrict__ bt, const int* __restrict__ flagp)
{
    int isbf = *flagp;
    long row = blockIdx.x;
    float v[4];
    float s = 0.f, q = 0.f;
#pragma unroll
    for (int i = 0; i < 4; i++) {
        long idx = row * H_ + threadIdx.x + i * 256;
        v[i] = isbf ? bf2f(((const bf16_t*)buf)[idx]) : ((const float*)buf)[idx];
        s += v[i];
        q += v[i] * v[i];
    }
#pragma unroll
    for (int off = 32; off; off >>= 1) {
        s += __shfl_down(s, off);
        q += __shfl_down(q, off);
    }
    __shared__ float ls[4], lq[4];
    __shared__ float smu, sri;
    int wid = threadIdx.x >> 6, lane = threadIdx.x & 63;
    if (lane == 0) { ls[wid] = s; lq[wid] = q; }
    __syncthreads();
    if (threadIdx.x == 0) {
        float S = ls[0] + ls[1] + ls[2] + ls[3];
        float Q = lq[0] + lq[1] + lq[2] + lq[3];
        float mu = S * (1.f / H_);
        smu = mu;
        sri = rsqrtf(Q * (1.f / H_) - mu * mu + EPS);
    }
    __syncthreads();
    float mu = smu, ri = sri;
#pragma unroll
    for (int i = 0; i < 4; i++) {
        long idx = row * H_ + threadIdx.x + i * 256;
        int k = threadIdx.x + i * 256;
        float o = (v[i] - mu) * ri * g[k] + bt[k];
        if (isbf) ((bf16_t*)buf)[idx] = f2bf(o);
        else      ((float*)buf)[idx] = o;
    }
}

// ---------------------------------------------------------------------------
// Pre-GEMM: P[m,j] = sum_k xn[m,k] * W[j,k] + bias[j]  (x-part of W, [H,2H]).
// xn bf16 [16384,1024]; W flag-dtype; P bf16. 128x128 tile, 8x8 micro-tile.
__global__ __launch_bounds__(256) void gemm_pre(
    const bf16_t* __restrict__ A,
    const void* __restrict__ Wu, const void* __restrict__ Wr, const void* __restrict__ Wo,
    const float* __restrict__ bias3,   // [3,H] canonical: bu, br, bo
    bf16_t* __restrict__ Pu, bf16_t* __restrict__ Pr, bf16_t* __restrict__ Po,
    const int* __restrict__ flagp)
{
    int isbf = *flagp;
    const void* W;
    const float* bias = bias3 + (long)blockIdx.z * H_;
    bf16_t* C;
    if (blockIdx.z == 0)      { W = Wu; C = Pu; }
    else if (blockIdx.z == 1) { W = Wr; C = Pr; }
    else                      { W = Wo; C = Po; }

    __shared__ float sa[8][128];
    __shared__ float sb[8][128];
    float acc[8][8];
#pragma unroll
    for (int i = 0; i < 8; i++)
#pragma unroll
        for (int j = 0; j < 8; j++) acc[i][j] = 0.f;

    int tx = threadIdx.x % 16, ty = threadIdx.x / 16;
    int m0 = blockIdx.x * 128, n0 = blockIdx.y * 128;
    int lr = threadIdx.x >> 1;          // 0..127
    int lc = (threadIdx.x & 1) * 4;     // 0 or 4

    for (int kt = 0; kt < H_; kt += 8) {
        ushort4 av = *(const ushort4*)(A + (long)(m0 + lr) * H_ + kt + lc);
        float w0, w1, w2, w3;
        long woff = (long)(n0 + lr) * (2 * H_) + kt + lc;
        if (isbf) {
            ushort4 bv = *(const ushort4*)((const bf16_t*)W + woff);
            w0 = bf2f(bv.x); w1 = bf2f(bv.y); w2 = bf2f(bv.z); w3 = bf2f(bv.w);
        } else {
            float4 bv = *(const float4*)((const float*)W + woff);
            w0 = bv.x; w1 = bv.y; w2 = bv.z; w3 = bv.w;
        }
        sa[lc + 0][lr] = bf2f(av.x); sa[lc + 1][lr] = bf2f(av.y);
        sa[lc + 2][lr] = bf2f(av.z); sa[lc + 3][lr] = bf2f(av.w);
        sb[lc + 0][lr] = w0; sb[lc + 1][lr] = w1;
        sb[lc + 2][lr] = w2; sb[lc + 3][lr] = w3;
        __syncthreads();
#pragma unroll
        for (int k = 0; k < 8; k++) {
            float ar[8], brg[8];
#pragma unroll
            for (int i = 0; i < 8; i++) ar[i] = sa[k][ty * 8 + i];
#pragma unroll
            for (int j = 0; j < 8; j++) brg[j] = sb[k][tx * 8 + j];
#pragma unroll
            for (int i = 0; i < 8; i++)
#pragma unroll
                for (int j = 0; j < 8; j++) acc[i][j] += ar[i] * brg[j];
        }
        __syncthreads();
    }
#pragma unroll
    for (int i = 0; i < 8; i++) {
        long m = m0 + ty * 8 + i;
#pragma unroll
        for (int j = 0; j < 8; j++) {
            int n = n0 + tx * 8 + j;
            C[m * H_ + n] = f2bf(acc[i][j] + bias[n]);
        }
    }
}

// ---------------------------------------------------------------------------
// Step kernel 1: nh = LN(h) (redundant per block), then u and r columns.
// Wh slices are canonical bf16 [H,H]. grid = 64 blocks x 256 threads.
__global__ __launch_bounds__(256) void step_ur(
    int t,
    const bf16_t* __restrict__ Whu, const bf16_t* __restrict__ Whr,
    const float* __restrict__ st_g, const float* __restrict__ st_b,
    const bf16_t* __restrict__ Pu, const bf16_t* __restrict__ Pr,
    const float* __restrict__ h_ws, float* __restrict__ u_ws, float* __restrict__ rnh_ws)
{
    __shared__ float nh_s[8 * 1028];
    __shared__ float wt[32 * 260];
    __shared__ float mu_s[8], ri_s[8];

    int tid = threadIdx.x;
    int wid = tid >> 6, lane = tid & 63;

    for (int b = wid; b < 8; b += 4) {
        float s = 0.f, q = 0.f;
#pragma unroll
        for (int i = 0; i < 16; i++) {
            float v = h_ws[b * H_ + lane + i * 64];
            s += v; q += v * v;
        }
#pragma unroll
        for (int off = 32; off; off >>= 1) {
            s += __shfl_down(s, off);
            q += __shfl_down(q, off);
        }
        if (lane == 0) {
            float mu = s * (1.f / H_);
            mu_s[b] = mu;
            ri_s[b] = rsqrtf(q * (1.f / H_) - mu * mu + EPS);
        }
    }
    __syncthreads();
    for (int i = tid; i < 8 * H_; i += 256) {
        int b = i >> 10, k = i & 1023;
        nh_s[b * 1028 + k] = (h_ws[i] - mu_s[b]) * ri_s[b] * st_g[k] + st_b[k];
    }

    int c = tid >> 3, b = tid & 7;     // c: 0..31 (0..15 u-cols, 16..31 r-cols)
    int j = blockIdx.x * 16 + (c & 15);
    float acc = 0.f;

    for (int k0 = 0; k0 < H_; k0 += 256) {
        __syncthreads();
        for (int i = tid; i < 32 * 256; i += 256) {
            int cc = i >> 8, kk = i & 255;
            long jg = blockIdx.x * 16 + (cc & 15);
            const bf16_t* Wsrc = (cc < 16) ? Whu : Whr;
            wt[cc * 260 + kk] = bf2f(Wsrc[jg * H_ + k0 + kk]);
        }
        __syncthreads();
        const float* nr = nh_s + b * 1028 + k0;
        const float* wr = wt + c * 260;
#pragma unroll 4
        for (int kk = 0; kk < 256; kk += 4) {
            float4 nv = *(const float4*)(nr + kk);
            float4 wv = *(const float4*)(wr + kk);
            acc += nv.x * wv.x + nv.y * wv.y + nv.z * wv.z + nv.w * wv.w;
        }
    }

    long p = ((long)b * S_ + t) * H_ + j;
    if (c < 16) {
        u_ws[b * H_ + j] = 1.f / (1.f + expf(-(bf2f(Pu[p]) + acc)));
    } else {
        float rval = 1.f / (1.f + expf(-(bf2f(Pr[p]) + acc)));
        rnh_ws[b * H_ + j] = rval * nh_s[b * 1028 + j];
    }
}

// ---------------------------------------------------------------------------
// Step kernel 2: c = tanh(Po + (r*nh) @ Who^T), h = (1-u)h + u*c; write h to
// out in flag dtype. grid = 64 blocks x 256 threads.
__global__ __launch_bounds__(256) void step_c(
    int t, const bf16_t* __restrict__ Who,
    const bf16_t* __restrict__ Po, const float* __restrict__ rnh_ws,
    const float* __restrict__ u_ws, float* __restrict__ h_ws,
    void* __restrict__ outb, const int* __restrict__ flagp)
{
    int isbf = *flagp;
    __shared__ float rn_s[8 * 1028];
    __shared__ float wt[16 * 260];
    __shared__ float part[256];

    int tid = threadIdx.x;
    for (int i = tid; i < 8 * H_; i += 256)
        rn_s[(i >> 10) * 1028 + (i & 1023)] = rnh_ws[i];

    int half = tid >> 7, rem = tid & 127;
    int c = rem >> 3, b = rem & 7;
    int j = blockIdx.x * 16 + c;
    float acc = 0.f;

    for (int k0 = 0; k0 < H_; k0 += 256) {
        __syncthreads();
        for (int i = tid; i < 16 * 256; i += 256) {
            int cc = i >> 8, kk = i & 255;
            wt[cc * 260 + kk] = bf2f(Who[(long)(blockIdx.x * 16 + cc) * H_ + k0 + kk]);
        }
        __syncthreads();
        if ((k0 >> 9) == half) {
            const float* nr = rn_s + b * 1028 + k0;
            const float* wr = wt + c * 260;
#pragma unroll 4
            for (int kk = 0; kk < 256; kk += 4) {
                float4 nv = *(const float4*)(nr + kk);
                float4 wv = *(const float4*)(wr + kk);
                acc += nv.x * wv.x + nv.y * wv.y + nv.z * wv.z + nv.w * wv.w;
            }
        }
    }
    part[tid] = acc;
    __syncthreads();
    if (half == 0) {
        float tot = acc + part[tid + 128];
        long p = ((long)b * S_ + t) * H_ + j;
        float cval = tanhf(bf2f(Po[p]) + tot);
        float u = u_ws[b * H_ + j];
        float hv = h_ws[b * H_ + j];
        float hn = (1.f - u) * hv + u * cval;
        h_ws[b * H_ + j] = hn;
        if (isbf) ((bf16_t*)outb)[p] = f2bf(hn);
        else      ((float*)outb)[p] = hn;
    }
}

// ---------------------------------------------------------------------------
extern "C" void kernel_launch(void* const* d_in, const int* in_sizes, int n_in,
                              void* d_out, int out_size, void* d_ws, size_t ws_size,
                              hipStream_t stream)
{
    const void* input = d_in[0];
    const void* in_g  = d_in[1];
    const void* in_b  = d_in[2];
    const void* st_g  = d_in[3];
    const void* st_b  = d_in[4];
    const void* Wu    = d_in[5];
    const void* bu    = d_in[6];
    const void* Wr    = d_in[7];
    const void* br    = d_in[8];
    const void* Wo    = d_in[9];
    const void* bo    = d_in[10];
    const void* ln_g  = d_in[11];
    const void* ln_b  = d_in[12];

    const long NTOK = (long)B_ * S_ * H_;  // 16777216

    // ws layout (~102 MB total)
    char* base = (char*)d_ws;
    int*   flag   = (int*)base;                                 // 256 B header
    float* h_ws   = (float*)(base + 256);                       // 32 KB
    float* u_ws   = h_ws + B_ * H_;                             // 32 KB
    float* rnh_ws = u_ws + B_ * H_;                             // 32 KB
    float* vecs   = rnh_ws + B_ * H_;                           // 9 x 4 KB
    float* c_stg = vecs + 0 * H_;
    float* c_stb = vecs + 1 * H_;
    float* c_ing = vecs + 2 * H_;
    float* c_inb = vecs + 3 * H_;
    float* c_lng = vecs + 4 * H_;
    float* c_lnb = vecs + 5 * H_;
    float* c_bias3 = vecs + 6 * H_;                             // bu, br, bo
    bf16_t* Whu = (bf16_t*)(vecs + 9 * H_);                     // 2 MB
    bf16_t* Whr = Whu + (long)H_ * H_;                          // 2 MB
    bf16_t* Who = Whr + (long)H_ * H_;                          // 2 MB
    bf16_t* Pu  = Who + (long)H_ * H_;                          // 32 MB
    bf16_t* Pr  = Pu + NTOK;                                    // 32 MB
    bf16_t* Po  = Pr + NTOK;                                    // 32 MB

    // xn (bf16, 32 MB) lives in d_out: dead after gemm_pre, before scan writes.
    bf16_t* xn = (bf16_t*)d_out;

    detect_flag<<<1, 1, 0, stream>>>((const unsigned*)in_g, flag);

    canon_vec<<<dim3(H_ / 256, 9), 256, 0, stream>>>(
        st_g, st_b, in_g, in_b, ln_g, ln_b, bu, br, bo, vecs, flag);
    canon_wh<<<dim3(H_, 3), 256, 0, stream>>>(Wu, Wr, Wo, Whu, Whr, Who, flag);

    hipMemsetAsync(h_ws, 0, B_ * H_ * sizeof(float), stream);

    ln_in<<<B_ * S_, 256, 0, stream>>>(input, c_ing, c_inb, xn, flag);

    gemm_pre<<<dim3(128, 8, 3), 256, 0, stream>>>(
        xn, Wu, Wr, Wo, c_bias3, Pu, Pr, Po, flag);

    for (int t = 0; t < S_; t++) {
        step_ur<<<64, 256, 0, stream>>>(t, Whu, Whr, c_stg, c_stb, Pu, Pr,
                                        h_ws, u_ws, rnh_ws);
        step_c<<<64, 256, 0, stream>>>(t, Who, Po, rnh_ws, u_ws, h_ws, d_out, flag);
    }

    ln_out<<<B_ * S_, 256, 0, stream>>>(d_out, c_lng, c_lnb, flag);
}